// Round 13
// baseline (124.121 us; speedup 1.0000x reference)
//
#include <hip/hip_runtime.h>

#define Bn 4096
#define Dn 66
#define Hn 512
#define MAGIC 0x5A5A5A5Au

typedef __attribute__((ext_vector_type(8))) short short8;
typedef __attribute__((ext_vector_type(4))) float f32x4;

__device__ __forceinline__ unsigned short f2bf(float x) {
    union { float f; unsigned u; } v; v.f = x;
    unsigned r = v.u + 0x7fffu + ((v.u >> 16) & 1u);   // RNE
    return (unsigned short)(r >> 16);
}
__device__ __forceinline__ float bf2f(unsigned short h) {
    union { float f; unsigned u; } v; v.u = ((unsigned)h) << 16; return v.f;
}

// Layouts:
//   A-frag (block-local) tile ks: lane l holds A[(l&15)][ks*32 + (l>>4)*8 + j]
//       at (ks*64 + l)*8 + j                  -> conflict-free ds_read_b128
//   WQ interleaved B-frag tile (ct, ks): W2-frag at ((ct*16+ks)*64+l)*16 + 0..7,
//       Cm-frag at +8..15                     -> 2KB contiguous per wave
//   W3P B-frag tile (jt, ks): ((jt*16+ks)*64 + l)*8 + j
//
// Single kernel: pack (waves 0-2, hidden behind phase A) -> device flag barrier
// -> MFMA phases. Flags live in ws (poisoned 0xAA != MAGIC each iteration).

__global__ __launch_bounds__(1024, 4) void k_all(
    const float* __restrict__ xs, const float* __restrict__ tt,
    const float* __restrict__ W1, const float* __restrict__ b1,
    const float* __restrict__ W2, const float* __restrict__ b2,
    const float* __restrict__ W3, const float* __restrict__ b3,
    unsigned short* __restrict__ WQ, unsigned short* __restrict__ W3P,
    unsigned int* __restrict__ flags, float* __restrict__ out)
{
    __shared__ __align__(16) unsigned short sA[2*8192];  // h1hi|s1' -> h2hi|h2lo (32 KB)
    __shared__ float sX[67*16];
    __shared__ float sW3[1088];        // 16 contiguous W3 rows (this block's pack ct)
    __shared__ float sRed[16*16];

    const int tid = threadIdx.x, lane = tid & 63, wv = tid >> 6;   // wv 0..15
    const int bid = blockIdx.x;
    const int rt = bid, r0 = rt*16;
    const int n = lane & 15, kg = lane >> 4;
    const int rot = (bid >> 3) & 15;

    // ---- stage x^T (row 66 = t) + this block's W3 pack rows ----
    for (int idx = tid; idx < 67*16; idx += 1024) {
        const int i = idx >> 4, r = idx & 15;
        sX[idx] = (i < Dn) ? xs[(size_t)(r0+r)*Dn + i] : tt[r0+r];
    }
    {
        const int ct = bid >> 3;
        const float* src = &W3[(size_t)(ct*16)*Dn];   // 1056 contiguous floats
        for (int k = tid; k < 1056; k += 1024) sW3[k] = src[k];
    }
    __syncthreads();

    // ---- pack (waves 0-2) ----
    if (wv < 2) {
        const int ct = bid >> 3;
        const int ks = 2*(bid & 7) + wv;
        const int abase = ks*32 + kg*8;
        float w2v[8], m[8];
        #pragma unroll
        for (int j = 0; j < 8; ++j) {
            w2v[j] = W2[(size_t)(abase + j)*Hn + ct*16 + n];
            m[j] = 0.f;
        }
        #pragma unroll 2
        for (int i = 0; i < Dn; ++i) {
            const float w3 = sW3[n*66 + i];
            const float4 w1a = *(const float4*)&W1[(size_t)i*Hn + abase];
            const float4 w1b = *(const float4*)&W1[(size_t)i*Hn + abase + 4];
            m[0] = fmaf(w3, w1a.x, m[0]); m[1] = fmaf(w3, w1a.y, m[1]);
            m[2] = fmaf(w3, w1a.z, m[2]); m[3] = fmaf(w3, w1a.w, m[3]);
            m[4] = fmaf(w3, w1b.x, m[4]); m[5] = fmaf(w3, w1b.y, m[5]);
            m[6] = fmaf(w3, w1b.z, m[6]); m[7] = fmaf(w3, w1b.w, m[7]);
        }
        short8 pw, pc;
        #pragma unroll
        for (int j = 0; j < 8; ++j) {
            pw[j] = (short)f2bf(w2v[j]);
            pc[j] = (short)f2bf(w2v[j] * m[j]);
        }
        const size_t off = ((size_t)(ct*16 + ks)*64 + lane)*16;
        *(short8*)&WQ[off]     = pw;
        *(short8*)&WQ[off + 8] = pc;
    } else if (wv == 2 && bid < 80) {
        const int tix = bid;                  // jt*16 + ks
        const int ks = tix & 15;
        const int j_out = (tix >> 4)*16 + n;
        const int abase = ks*32 + kg*8;
        short8 p;
        #pragma unroll
        for (int j = 0; j < 8; ++j)
            p[j] = (j_out < Dn) ? (short)f2bf(W3[(size_t)(abase + j)*Dn + j_out]) : (short)0;
        *(short8*)&W3P[((size_t)tix*64 + lane)*8] = p;
    }

    // ---- phase A: z1 (fp32); wave wv owns cols [wv*32, wv*32+32); rotated i ----
    {
        const int rg = lane & 7, cg = lane >> 3;
        const int c0 = wv*32 + cg*4;
        const int irot = (bid >> 3) & 31;
        float z[2][4];
        {
            const float4 b4 = *(const float4*)&b1[c0];
            z[0][0]=b4.x; z[0][1]=b4.y; z[0][2]=b4.z; z[0][3]=b4.w;
            z[1][0]=b4.x; z[1][1]=b4.y; z[1][2]=b4.z; z[1][3]=b4.w;
        }
        #pragma unroll 2
        for (int s = 0; s < 67; ++s) {
            int i = s + irot; if (i >= 67) i -= 67;
            const float2 xf = *(const float2*)&sX[i*16 + 2*rg];
            const float4 wA = *(const float4*)&W1[(size_t)i*Hn + c0];
            const float ww[4] = {wA.x, wA.y, wA.z, wA.w};
            #pragma unroll
            for (int j = 0; j < 4; ++j) {
                z[0][j] = fmaf(xf.x, ww[j], z[0][j]);
                z[1][j] = fmaf(xf.y, ww[j], z[1][j]);
            }
        }
        const int kgrp = cg >> 1, joff = (cg & 1)*4;
        #pragma unroll
        for (int rr = 0; rr < 2; ++rr) {
            const int r = 2*(lane & 7) + rr;
            ushort4 phi, ps;
            unsigned short* PH = (unsigned short*)&phi;
            unsigned short* PS = (unsigned short*)&ps;
            #pragma unroll
            for (int j = 0; j < 4; ++j) {
                const float zv = z[rr][j];
                const float sg = 1.f / (1.f + __expf(-zv));
                PH[j] = f2bf(zv * sg);
                PS[j] = f2bf(sg * (1.f + zv * (1.f - sg)));
            }
            const int off = (wv*64 + r + 16*kgrp)*8 + joff;
            *(ushort4*)&sA[off]        = phi;
            *(ushort4*)&sA[8192 + off] = ps;
        }
    }
    __syncthreads();   // sA ready; pack stores drained (vmcnt0 at barrier)

    // ---- device barrier: all blocks' pack visible before WQ/W3P reads ----
    if (tid == 0)
        __hip_atomic_store(&flags[bid], MAGIC, __ATOMIC_RELEASE, __HIP_MEMORY_SCOPE_AGENT);
    if (tid < 256) {
        while (__hip_atomic_load(&flags[tid], __ATOMIC_ACQUIRE, __HIP_MEMORY_SCOPE_AGENT) != MAGIC)
            __builtin_amdgcn_s_sleep(1);
    }
    __syncthreads();

    // ---- phase B: z2 = h1hi@W2 + b2, v = s1'@Cmat; prefetched weights ----
    const int ctb = wv*2;
    f32x4 zac[2], vac[2];
    #pragma unroll
    for (int ti = 0; ti < 2; ++ti) {
        const float bz = b2[(ctb + ti)*16 + n];
        zac[ti] = (f32x4){bz, bz, bz, bz};
        vac[ti] = (f32x4){0.f, 0.f, 0.f, 0.f};
    }
    short8 wbuf[2][2], qbuf[2][2];
    #pragma unroll
    for (int ti = 0; ti < 2; ++ti) {
        const size_t wo = ((size_t)((ctb + ti)*16 + rot)*64 + lane)*16;
        wbuf[0][ti] = *(const short8*)&WQ[wo];
        qbuf[0][ti] = *(const short8*)&WQ[wo + 8];
    }
    #pragma unroll
    for (int s = 0; s < 16; ++s) {
        const int cur = s & 1, nxt = cur ^ 1;
        if (s < 15) {
            const int ksn = (s + 1 + rot) & 15;
            #pragma unroll
            for (int ti = 0; ti < 2; ++ti) {
                const size_t wo = ((size_t)((ctb + ti)*16 + ksn)*64 + lane)*16;
                wbuf[nxt][ti] = *(const short8*)&WQ[wo];
                qbuf[nxt][ti] = *(const short8*)&WQ[wo + 8];
            }
        }
        const int ks = (s + rot) & 15;
        const int ao = (ks*64 + lane)*8;
        const short8 ahi = *(const short8*)&sA[ao];
        const short8 as1 = *(const short8*)&sA[8192 + ao];
        #pragma unroll
        for (int ti = 0; ti < 2; ++ti) {
            zac[ti] = __builtin_amdgcn_mfma_f32_16x16x32_bf16(ahi, wbuf[cur][ti], zac[ti], 0, 0, 0);
            vac[ti] = __builtin_amdgcn_mfma_f32_16x16x32_bf16(as1, qbuf[cur][ti], vac[ti], 0, 0, 0);
        }
    }
    __syncthreads();   // all sA reads complete before h2 aliases it

    // ---- epilogue: h2 hi/lo -> sA; divergence partials ----
    float dp[4] = {0.f, 0.f, 0.f, 0.f};
    #pragma unroll
    for (int ti = 0; ti < 2; ++ti) {
        const int c = (ctb + ti)*16 + n;
        const int ks2 = c >> 5, kg2 = (c >> 3) & 3, j2 = c & 7;
        #pragma unroll
        for (int q = 0; q < 4; ++q) {
            const float z2 = zac[ti][q];
            const float sg = 1.f / (1.f + __expf(-z2));
            const float h2 = z2 * sg;
            dp[q] = fmaf(sg * (1.f + z2 * (1.f - sg)), vac[ti][q], dp[q]);
            const unsigned short hh = f2bf(h2);
            const int o = (ks2*64 + (kg*4 + q) + 16*kg2)*8 + j2;
            sA[o] = hh;
            sA[8192 + o] = f2bf(h2 - bf2f(hh));
        }
    }
    #pragma unroll
    for (int q = 0; q < 4; ++q) {
        float v = dp[q];
        v += __shfl_xor(v, 1, 64);
        v += __shfl_xor(v, 2, 64);
        v += __shfl_xor(v, 4, 64);
        v += __shfl_xor(v, 8, 64);
        if (n == 0) sRed[wv*16 + kg*4 + q] = v;
    }
    __syncthreads();

    // ---- divergence finalize ----
    if (tid < 16) {
        float s = 0.f;
        #pragma unroll
        for (int q = 0; q < 16; ++q) s += sRed[q*16 + tid];
        out[(size_t)Bn*Dn + r0 + tid] = -s;
    }

    // ---- phase C: out = h2 @ W3 + b3 (waves 0..4); rotated ks ----
    if (wv < 5) {
        const int jt = wv;
        const int j = jt*16 + n;
        const float bj = (j < Dn) ? b3[j] : 0.f;
        f32x4 oac = (f32x4){bj, bj, bj, bj};
        #pragma unroll 4
        for (int s = 0; s < 16; ++s) {
            const int ks = (s + rot) & 15;
            const int aoff = (ks*64 + lane)*8;
            const short8 ahi = *(const short8*)&sA[aoff];
            const short8 alo = *(const short8*)&sA[8192 + aoff];
            const short8 wf  = *(const short8*)&W3P[((size_t)(jt*16 + ks)*64 + lane)*8];
            oac = __builtin_amdgcn_mfma_f32_16x16x32_bf16(ahi, wf, oac, 0, 0, 0);
            oac = __builtin_amdgcn_mfma_f32_16x16x32_bf16(alo, wf, oac, 0, 0, 0);
        }
        if (j < Dn) {
            #pragma unroll
            for (int q = 0; q < 4; ++q)
                out[(size_t)(r0 + kg*4 + q)*Dn + j] = oac[q];
        }
    }
}

extern "C" void kernel_launch(void* const* d_in, const int* in_sizes, int n_in,
                              void* d_out, int out_size, void* d_ws, size_t ws_size,
                              hipStream_t stream)
{
    const float* xs = (const float*)d_in[0];
    const float* t  = (const float*)d_in[1];
    const float* W1 = (const float*)d_in[2];
    const float* b1 = (const float*)d_in[3];
    const float* W2 = (const float*)d_in[4];
    const float* b2 = (const float*)d_in[5];
    const float* W3 = (const float*)d_in[6];
    const float* b3 = (const float*)d_in[7];
    float* out = (float*)d_out;

    char* ws = (char*)d_ws;
    unsigned short* WQ   = (unsigned short*)(ws);                // 1 MB interleaved W2|Cm
    unsigned short* W3P  = (unsigned short*)(ws + 1048576);      // 80 KB
    unsigned int*  flags = (unsigned int*)(ws + 1130496);        // 1 KB (poisoned != MAGIC)

    k_all<<<256, 1024, 0, stream>>>(xs, t, W1, b1, W2, b2, W3, b3, WQ, W3P, flags, out);
}

// Round 14
// 107.775 us; speedup vs baseline: 1.1517x; 1.1517x over previous
//
#include <hip/hip_runtime.h>

#define Bn 4096
#define Dn 66
#define Hn 512

typedef __attribute__((ext_vector_type(8))) short short8;
typedef __attribute__((ext_vector_type(4))) float f32x4;

__device__ __forceinline__ unsigned short f2bf(float x) {
    union { float f; unsigned u; } v; v.f = x;
    unsigned r = v.u + 0x7fffu + ((v.u >> 16) & 1u);   // RNE
    return (unsigned short)(r >> 16);
}
__device__ __forceinline__ float bf2f(unsigned short h) {
    union { float f; unsigned u; } v; v.u = ((unsigned)h) << 16; return v.f;
}

// Layouts:
//   A-frag (block-local) tile ks: lane l holds A[(l&15)][ks*32 + (l>>4)*8 + j]
//       at (ks*64 + l)*8 + j                  -> conflict-free ds_read_b128
//   WQ interleaved B-frag tile (ct, ks): W2-frag at ((ct*16+ks)*64+l)*16 + 0..7,
//       Cm-frag at +8..15                     -> 2KB contiguous per wave
//   W3P B-frag tile (jt, ks): ((jt*16+ks)*64 + l)*8 + j

// ============ k_pack (74 blocks x 512) — R12 verbatim ============
__global__ __launch_bounds__(512, 2) void k_pack(
    const float* __restrict__ W1, const float* __restrict__ W2,
    const float* __restrict__ W3,
    unsigned short* __restrict__ WQ, unsigned short* __restrict__ W3P)
{
    __shared__ float sW3[16*68];
    const int bid = blockIdx.x, tid = threadIdx.x;
    const int lane = tid & 63, wv = tid >> 6;

    if (bid < 64) {
        const int ct = bid >> 1;
        {
            const int r = tid >> 5, ii = tid & 31;
            const float* src = &W3[(size_t)(ct*16 + r)*Dn];
            sW3[r*68 + ii] = src[ii];
            sW3[r*68 + ii + 32] = src[ii + 32];
            if (ii < 2) sW3[r*68 + ii + 64] = src[ii + 64];
        }
        __syncthreads();
        const int ks = (bid & 1)*8 + wv;
        const int n = lane & 15, kg = lane >> 4;
        const int c = ct*16 + n;
        const int abase = ks*32 + kg*8;
        float w2v[8], m[8];
        #pragma unroll
        for (int j = 0; j < 8; ++j) {
            w2v[j] = W2[(size_t)(abase + j)*Hn + c];
            m[j] = 0.f;
        }
        #pragma unroll 2
        for (int i = 0; i < Dn; ++i) {
            const float w3 = sW3[n*68 + i];
            const float4 w1a = *(const float4*)&W1[(size_t)i*Hn + abase];
            const float4 w1b = *(const float4*)&W1[(size_t)i*Hn + abase + 4];
            m[0] = fmaf(w3, w1a.x, m[0]); m[1] = fmaf(w3, w1a.y, m[1]);
            m[2] = fmaf(w3, w1a.z, m[2]); m[3] = fmaf(w3, w1a.w, m[3]);
            m[4] = fmaf(w3, w1b.x, m[4]); m[5] = fmaf(w3, w1b.y, m[5]);
            m[6] = fmaf(w3, w1b.z, m[6]); m[7] = fmaf(w3, w1b.w, m[7]);
        }
        short8 pw, pc;
        #pragma unroll
        for (int j = 0; j < 8; ++j) {
            pw[j] = (short)f2bf(w2v[j]);
            pc[j] = (short)f2bf(w2v[j] * m[j]);
        }
        const size_t off = ((size_t)(ct*16 + ks)*64 + lane)*16;
        *(short8*)&WQ[off]     = pw;
        *(short8*)&WQ[off + 8] = pc;
    } else {
        const int tix = (bid - 64)*8 + wv;
        if (tix < 80) {
            const int ks = tix & 15;
            const int n = lane & 15, kg = lane >> 4;
            const int j_out = (tix >> 4)*16 + n;
            const int abase = ks*32 + kg*8;
            short8 p;
            #pragma unroll
            for (int j = 0; j < 8; ++j)
                p[j] = (j_out < Dn) ? (short)f2bf(W3[(size_t)(abase + j)*Dn + j_out]) : (short)0;
            *(short8*)&W3P[((size_t)tix*64 + lane)*8] = p;
        }
    }
}

// ============ k_main: fused, grid 256 x 1024; rotation + prefetch; NO h1-lo ============
__global__ __launch_bounds__(1024, 4) void k_main(
    const float* __restrict__ xs, const float* __restrict__ tt,
    const float* __restrict__ W1, const float* __restrict__ b1,
    const unsigned short* __restrict__ WQ, const float* __restrict__ b2,
    const unsigned short* __restrict__ W3P, const float* __restrict__ b3,
    float* __restrict__ out)
{
    __shared__ __align__(16) unsigned short sA[2*8192];  // h1hi|s1' -> h2hi|h2lo (32 KB)
    __shared__ float sX[67*16];
    __shared__ float sRed[16*16];

    const int tid = threadIdx.x, lane = tid & 63, wv = tid >> 6;   // wv 0..15
    const int rt = blockIdx.x, r0 = rt*16;
    const int n = lane & 15, kg = lane >> 4;
    const int rot = (blockIdx.x >> 3) & 15;

    // ---- stage x^T (row 66 = t) ----
    for (int idx = tid; idx < 67*16; idx += 1024) {
        const int i = idx >> 4, r = idx & 15;
        sX[idx] = (i < Dn) ? xs[(size_t)(r0+r)*Dn + i] : tt[r0+r];
    }
    __syncthreads();

    // ---- phase A: z1 (fp32); wave wv owns cols [wv*32, wv*32+32); rotated i ----
    {
        const int rg = lane & 7, cg = lane >> 3;
        const int c0 = wv*32 + cg*4;
        const int irot = (blockIdx.x >> 3) & 31;
        float z[2][4];
        {
            const float4 b4 = *(const float4*)&b1[c0];
            z[0][0]=b4.x; z[0][1]=b4.y; z[0][2]=b4.z; z[0][3]=b4.w;
            z[1][0]=b4.x; z[1][1]=b4.y; z[1][2]=b4.z; z[1][3]=b4.w;
        }
        #pragma unroll 2
        for (int s = 0; s < 67; ++s) {
            int i = s + irot; if (i >= 67) i -= 67;
            const float2 xf = *(const float2*)&sX[i*16 + 2*rg];
            const float4 wA = *(const float4*)&W1[(size_t)i*Hn + c0];
            const float ww[4] = {wA.x, wA.y, wA.z, wA.w};
            #pragma unroll
            for (int j = 0; j < 4; ++j) {
                z[0][j] = fmaf(xf.x, ww[j], z[0][j]);
                z[1][j] = fmaf(xf.y, ww[j], z[1][j]);
            }
        }
        const int kgrp = cg >> 1, joff = (cg & 1)*4;
        #pragma unroll
        for (int rr = 0; rr < 2; ++rr) {
            const int r = 2*(lane & 7) + rr;
            ushort4 phi, ps;
            unsigned short* PH = (unsigned short*)&phi;
            unsigned short* PS = (unsigned short*)&ps;
            #pragma unroll
            for (int j = 0; j < 4; ++j) {
                const float zv = z[rr][j];
                const float sg = 1.f / (1.f + __expf(-zv));
                PH[j] = f2bf(zv * sg);
                PS[j] = f2bf(sg * (1.f + zv * (1.f - sg)));
            }
            const int off = (wv*64 + r + 16*kgrp)*8 + joff;
            *(ushort4*)&sA[off]        = phi;
            *(ushort4*)&sA[8192 + off] = ps;
        }
    }
    __syncthreads();

    // ---- phase B: z2 = h1hi@W2 + b2, v = s1'@Cmat; prefetched weights ----
    const int ctb = wv*2;
    f32x4 zac[2], vac[2];
    #pragma unroll
    for (int ti = 0; ti < 2; ++ti) {
        const float bz = b2[(ctb + ti)*16 + n];
        zac[ti] = (f32x4){bz, bz, bz, bz};
        vac[ti] = (f32x4){0.f, 0.f, 0.f, 0.f};
    }
    short8 wbuf[2][2], qbuf[2][2];
    #pragma unroll
    for (int ti = 0; ti < 2; ++ti) {
        const size_t wo = ((size_t)((ctb + ti)*16 + rot)*64 + lane)*16;
        wbuf[0][ti] = *(const short8*)&WQ[wo];
        qbuf[0][ti] = *(const short8*)&WQ[wo + 8];
    }
    #pragma unroll
    for (int s = 0; s < 16; ++s) {
        const int cur = s & 1, nxt = cur ^ 1;
        if (s < 15) {
            const int ksn = (s + 1 + rot) & 15;
            #pragma unroll
            for (int ti = 0; ti < 2; ++ti) {
                const size_t wo = ((size_t)((ctb + ti)*16 + ksn)*64 + lane)*16;
                wbuf[nxt][ti] = *(const short8*)&WQ[wo];
                qbuf[nxt][ti] = *(const short8*)&WQ[wo + 8];
            }
        }
        const int ks = (s + rot) & 15;
        const int ao = (ks*64 + lane)*8;
        const short8 ahi = *(const short8*)&sA[ao];
        const short8 as1 = *(const short8*)&sA[8192 + ao];
        #pragma unroll
        for (int ti = 0; ti < 2; ++ti) {
            zac[ti] = __builtin_amdgcn_mfma_f32_16x16x32_bf16(ahi, wbuf[cur][ti], zac[ti], 0, 0, 0);
            vac[ti] = __builtin_amdgcn_mfma_f32_16x16x32_bf16(as1, qbuf[cur][ti], vac[ti], 0, 0, 0);
        }
    }
    __syncthreads();   // all sA reads complete before h2 aliases it

    // ---- epilogue: h2 hi/lo -> sA[0..8192]/sA[8192..]; divergence partials ----
    float dp[4] = {0.f, 0.f, 0.f, 0.f};
    #pragma unroll
    for (int ti = 0; ti < 2; ++ti) {
        const int c = (ctb + ti)*16 + n;
        const int ks2 = c >> 5, kg2 = (c >> 3) & 3, j2 = c & 7;
        #pragma unroll
        for (int q = 0; q < 4; ++q) {
            const float z2 = zac[ti][q];
            const float sg = 1.f / (1.f + __expf(-z2));
            const float h2 = z2 * sg;
            dp[q] = fmaf(sg * (1.f + z2 * (1.f - sg)), vac[ti][q], dp[q]);
            const unsigned short hh = f2bf(h2);
            const int o = (ks2*64 + (kg*4 + q) + 16*kg2)*8 + j2;
            sA[o] = hh;
            sA[8192 + o] = f2bf(h2 - bf2f(hh));
        }
    }
    #pragma unroll
    for (int q = 0; q < 4; ++q) {
        float v = dp[q];
        v += __shfl_xor(v, 1, 64);
        v += __shfl_xor(v, 2, 64);
        v += __shfl_xor(v, 4, 64);
        v += __shfl_xor(v, 8, 64);
        if (n == 0) sRed[wv*16 + kg*4 + q] = v;
    }
    __syncthreads();

    // ---- divergence finalize ----
    if (tid < 16) {
        float s = 0.f;
        #pragma unroll
        for (int q = 0; q < 16; ++q) s += sRed[q*16 + tid];
        out[(size_t)Bn*Dn + r0 + tid] = -s;
    }

    // ---- phase C: out = h2 @ W3 + b3 (waves 0..4); rotated ks ----
    if (wv < 5) {
        const int jt = wv;
        const int j = jt*16 + n;
        const float bj = (j < Dn) ? b3[j] : 0.f;
        f32x4 oac = (f32x4){bj, bj, bj, bj};
        #pragma unroll 4
        for (int s = 0; s < 16; ++s) {
            const int ks = (s + rot) & 15;
            const int aoff = (ks*64 + lane)*8;
            const short8 ahi = *(const short8*)&sA[aoff];
            const short8 alo = *(const short8*)&sA[8192 + aoff];
            const short8 wf  = *(const short8*)&W3P[((size_t)(jt*16 + ks)*64 + lane)*8];
            oac = __builtin_amdgcn_mfma_f32_16x16x32_bf16(ahi, wf, oac, 0, 0, 0);
            oac = __builtin_amdgcn_mfma_f32_16x16x32_bf16(alo, wf, oac, 0, 0, 0);
        }
        if (j < Dn) {
            #pragma unroll
            for (int q = 0; q < 4; ++q)
                out[(size_t)(r0 + kg*4 + q)*Dn + j] = oac[q];
        }
    }
}

extern "C" void kernel_launch(void* const* d_in, const int* in_sizes, int n_in,
                              void* d_out, int out_size, void* d_ws, size_t ws_size,
                              hipStream_t stream)
{
    const float* xs = (const float*)d_in[0];
    const float* t  = (const float*)d_in[1];
    const float* W1 = (const float*)d_in[2];
    const float* b1 = (const float*)d_in[3];
    const float* W2 = (const float*)d_in[4];
    const float* b2 = (const float*)d_in[5];
    const float* W3 = (const float*)d_in[6];
    const float* b3 = (const float*)d_in[7];
    float* out = (float*)d_out;

    char* ws = (char*)d_ws;
    unsigned short* WQ  = (unsigned short*)(ws);                 // 1 MB interleaved W2|Cm
    unsigned short* W3P = (unsigned short*)(ws + 1048576);       // 80 KB

    k_pack<<<74,  512,  0, stream>>>(W1, W2, W3, WQ, W3P);
    k_main<<<256, 1024, 0, stream>>>(xs, t, W1, b1, WQ, b2, W3P, b3, out);
}

// Round 15
// 106.337 us; speedup vs baseline: 1.1672x; 1.0135x over previous
//
#include <hip/hip_runtime.h>

#define Bn 4096
#define Dn 66
#define Hn 512

typedef __attribute__((ext_vector_type(8))) short short8;
typedef __attribute__((ext_vector_type(4))) float f32x4;

__device__ __forceinline__ unsigned short f2bf(float x) {
    union { float f; unsigned u; } v; v.f = x;
    unsigned r = v.u + 0x7fffu + ((v.u >> 16) & 1u);   // RNE
    return (unsigned short)(r >> 16);
}
__device__ __forceinline__ float bf2f(unsigned short h) {
    union { float f; unsigned u; } v; v.u = ((unsigned)h) << 16; return v.f;
}

// Layouts:
//   A-frag tile (rt, ks): lane l holds A[rt*16 + (l&15)][ks*32 + (l>>4)*8 + j]
//       at ((rt*16+ks)*64 + l)*8 + j          -> 1KB contiguous per wave
//   WQ interleaved B-frag tile (ct, ks): W2-frag at ((ct*16+ks)*64+l)*16 + 0..7,
//       Cm-frag at +8..15                     -> 2KB contiguous per wave
//   W3P B-frag tile (jt, ks): ((jt*16+ks)*64 + l)*8 + j

// ============ k_h1pack (586 blocks x 512): phase A at high occupancy + packing ============
// bid 0..511  : h1 half-tile: rt = bid>>1, cols [ (bid&1)*256, +256 ); writes h1hiP/s1P
// bid 512..575: WQ pack (W2 + Cmat fragments)
// bid 576..585: W3P pack
__global__ __launch_bounds__(512, 2) void k_h1pack(
    const float* __restrict__ xs, const float* __restrict__ tt,
    const float* __restrict__ W1, const float* __restrict__ b1,
    const float* __restrict__ W2, const float* __restrict__ W3,
    unsigned short* __restrict__ WQ, unsigned short* __restrict__ W3P,
    unsigned short* __restrict__ h1hiP, unsigned short* __restrict__ s1P)
{
    __shared__ float sLds[16*68];
    const int bid = blockIdx.x, tid = threadIdx.x;
    const int lane = tid & 63, wv = tid >> 6;          // wv 0..7

    if (bid < 512) {
        const int rt = bid >> 1, half = bid & 1;
        const int r0 = rt*16;
        // stage x^T (row 66 = t) into sLds[i*16 + r]
        for (int idx = tid; idx < 67*16; idx += 512) {
            const int i = idx >> 4, r = idx & 15;
            sLds[idx] = (i < Dn) ? xs[(size_t)(r0+r)*Dn + i] : tt[r0+r];
        }
        __syncthreads();
        const int rg = lane & 7, cg = lane >> 3;
        const int ks = half*8 + wv;                    // global ks-tile this wave owns
        const int c0 = ks*32 + cg*4;
        const int irot = (bid >> 3) & 31;
        float z[2][4];
        {
            const float4 b4 = *(const float4*)&b1[c0];
            z[0][0]=b4.x; z[0][1]=b4.y; z[0][2]=b4.z; z[0][3]=b4.w;
            z[1][0]=b4.x; z[1][1]=b4.y; z[1][2]=b4.z; z[1][3]=b4.w;
        }
        #pragma unroll 2
        for (int s = 0; s < 67; ++s) {
            int i = s + irot; if (i >= 67) i -= 67;
            const float2 xf = *(const float2*)&sLds[i*16 + 2*rg];
            const float4 wA = *(const float4*)&W1[(size_t)i*Hn + c0];
            const float ww[4] = {wA.x, wA.y, wA.z, wA.w};
            #pragma unroll
            for (int j = 0; j < 4; ++j) {
                z[0][j] = fmaf(xf.x, ww[j], z[0][j]);
                z[1][j] = fmaf(xf.y, ww[j], z[1][j]);
            }
        }
        const int kgrp = cg >> 1, joff = (cg & 1)*4;
        #pragma unroll
        for (int rr = 0; rr < 2; ++rr) {
            const int r = 2*rg + rr;
            ushort4 phi, ps;
            unsigned short* PH = (unsigned short*)&phi;
            unsigned short* PS = (unsigned short*)&ps;
            #pragma unroll
            for (int j = 0; j < 4; ++j) {
                const float zv = z[rr][j];
                const float sg = 1.f / (1.f + __expf(-zv));
                PH[j] = f2bf(zv * sg);
                PS[j] = f2bf(sg * (1.f + zv * (1.f - sg)));
            }
            const size_t off = ((size_t)(rt*16 + ks)*64 + r + 16*kgrp)*8 + joff;
            *(ushort4*)&h1hiP[off] = phi;
            *(ushort4*)&s1P [off] = ps;
        }
    } else if (bid < 576) {
        const int pb = bid - 512;
        const int ct = pb >> 1;
        {
            const int r = tid >> 5, ii = tid & 31;
            const float* src = &W3[(size_t)(ct*16 + r)*Dn];
            sLds[r*68 + ii] = src[ii];
            sLds[r*68 + ii + 32] = src[ii + 32];
            if (ii < 2) sLds[r*68 + ii + 64] = src[ii + 64];
        }
        __syncthreads();
        const int ks = (pb & 1)*8 + wv;
        const int n = lane & 15, kg = lane >> 4;
        const int c = ct*16 + n;
        const int abase = ks*32 + kg*8;
        float w2v[8], m[8];
        #pragma unroll
        for (int j = 0; j < 8; ++j) {
            w2v[j] = W2[(size_t)(abase + j)*Hn + c];
            m[j] = 0.f;
        }
        #pragma unroll 2
        for (int i = 0; i < Dn; ++i) {
            const float w3 = sLds[n*68 + i];
            const float4 w1a = *(const float4*)&W1[(size_t)i*Hn + abase];
            const float4 w1b = *(const float4*)&W1[(size_t)i*Hn + abase + 4];
            m[0] = fmaf(w3, w1a.x, m[0]); m[1] = fmaf(w3, w1a.y, m[1]);
            m[2] = fmaf(w3, w1a.z, m[2]); m[3] = fmaf(w3, w1a.w, m[3]);
            m[4] = fmaf(w3, w1b.x, m[4]); m[5] = fmaf(w3, w1b.y, m[5]);
            m[6] = fmaf(w3, w1b.z, m[6]); m[7] = fmaf(w3, w1b.w, m[7]);
        }
        short8 pw, pc;
        #pragma unroll
        for (int j = 0; j < 8; ++j) {
            pw[j] = (short)f2bf(w2v[j]);
            pc[j] = (short)f2bf(w2v[j] * m[j]);
        }
        const size_t off = ((size_t)(ct*16 + ks)*64 + lane)*16;
        *(short8*)&WQ[off]     = pw;
        *(short8*)&WQ[off + 8] = pc;
    } else {
        const int tix = (bid - 576)*8 + wv;   // jt*16 + ks, 80 tiles
        if (tix < 80) {
            const int ks = tix & 15;
            const int n = lane & 15, kg = lane >> 4;
            const int j_out = (tix >> 4)*16 + n;
            const int abase = ks*32 + kg*8;
            short8 p;
            #pragma unroll
            for (int j = 0; j < 8; ++j)
                p[j] = (j_out < Dn) ? (short)f2bf(W3[(size_t)(abase + j)*Dn + j_out]) : (short)0;
            *(short8*)&W3P[((size_t)tix*64 + lane)*8] = p;
        }
    }
}

// ============ k_BC: phases B+C, grid 256 x 1024; rotation + full register prefetch ============
__global__ __launch_bounds__(1024, 4) void k_BC(
    const unsigned short* __restrict__ h1hiP, const unsigned short* __restrict__ s1P,
    const unsigned short* __restrict__ WQ, const float* __restrict__ b2,
    const unsigned short* __restrict__ W3P, const float* __restrict__ b3,
    float* __restrict__ out)
{
    __shared__ __align__(16) unsigned short sH[8192];    // h2 hi (16 KB), A-frag local
    __shared__ __align__(16) unsigned short sL[8192];    // h2 lo (16 KB)
    __shared__ float sRed[16*16];

    const int tid = threadIdx.x, lane = tid & 63, wv = tid >> 6;   // wv 0..15
    const int rt = blockIdx.x, r0 = rt*16;
    const int n = lane & 15, kg = lane >> 4;
    const int rot = (blockIdx.x >> 3) & 15;

    // ---- phase B: z2 = h1hi@W2 + b2, v = s1'@Cmat; depth-1 register prefetch ----
    const int ctb = wv*2;
    f32x4 zac[2], vac[2];
    #pragma unroll
    for (int ti = 0; ti < 2; ++ti) {
        const float bz = b2[(ctb + ti)*16 + n];
        zac[ti] = (f32x4){bz, bz, bz, bz};
        vac[ti] = (f32x4){0.f, 0.f, 0.f, 0.f};
    }
    short8 wbuf[2][2], qbuf[2][2], abuf[2], sbuf[2];
    {
        const size_t ao = ((size_t)(rt*16 + rot)*64 + lane)*8;
        abuf[0] = *(const short8*)&h1hiP[ao];
        sbuf[0] = *(const short8*)&s1P[ao];
        #pragma unroll
        for (int ti = 0; ti < 2; ++ti) {
            const size_t wo = ((size_t)((ctb + ti)*16 + rot)*64 + lane)*16;
            wbuf[0][ti] = *(const short8*)&WQ[wo];
            qbuf[0][ti] = *(const short8*)&WQ[wo + 8];
        }
    }
    #pragma unroll
    for (int s = 0; s < 16; ++s) {
        const int cur = s & 1, nxt = cur ^ 1;
        if (s < 15) {
            const int ksn = (s + 1 + rot) & 15;
            const size_t ao = ((size_t)(rt*16 + ksn)*64 + lane)*8;
            abuf[nxt] = *(const short8*)&h1hiP[ao];
            sbuf[nxt] = *(const short8*)&s1P[ao];
            #pragma unroll
            for (int ti = 0; ti < 2; ++ti) {
                const size_t wo = ((size_t)((ctb + ti)*16 + ksn)*64 + lane)*16;
                wbuf[nxt][ti] = *(const short8*)&WQ[wo];
                qbuf[nxt][ti] = *(const short8*)&WQ[wo + 8];
            }
        }
        #pragma unroll
        for (int ti = 0; ti < 2; ++ti) {
            zac[ti] = __builtin_amdgcn_mfma_f32_16x16x32_bf16(abuf[cur], wbuf[cur][ti], zac[ti], 0, 0, 0);
            vac[ti] = __builtin_amdgcn_mfma_f32_16x16x32_bf16(sbuf[cur], qbuf[cur][ti], vac[ti], 0, 0, 0);
        }
    }

    // ---- epilogue: h2 hi/lo -> fresh LDS (no barrier needed before writes); dp ----
    float dp[4] = {0.f, 0.f, 0.f, 0.f};
    #pragma unroll
    for (int ti = 0; ti < 2; ++ti) {
        const int c = (ctb + ti)*16 + n;
        const int ks2 = c >> 5, kg2 = (c >> 3) & 3, j2 = c & 7;
        #pragma unroll
        for (int q = 0; q < 4; ++q) {
            const float z2 = zac[ti][q];
            const float sg = 1.f / (1.f + __expf(-z2));
            const float h2 = z2 * sg;
            dp[q] = fmaf(sg * (1.f + z2 * (1.f - sg)), vac[ti][q], dp[q]);
            const unsigned short hh = f2bf(h2);
            const int o = (ks2*64 + (kg*4 + q) + 16*kg2)*8 + j2;
            sH[o] = hh;
            sL[o] = f2bf(h2 - bf2f(hh));
        }
    }
    #pragma unroll
    for (int q = 0; q < 4; ++q) {
        float v = dp[q];
        v += __shfl_xor(v, 1, 64);
        v += __shfl_xor(v, 2, 64);
        v += __shfl_xor(v, 4, 64);
        v += __shfl_xor(v, 8, 64);
        if (n == 0) sRed[wv*16 + kg*4 + q] = v;
    }
    __syncthreads();

    // ---- divergence finalize ----
    if (tid < 16) {
        float s = 0.f;
        #pragma unroll
        for (int q = 0; q < 16; ++q) s += sRed[q*16 + tid];
        out[(size_t)Bn*Dn + r0 + tid] = -s;
    }

    // ---- phase C: out = h2 @ W3 + b3 (waves 0..4); rotated ks ----
    if (wv < 5) {
        const int jt = wv;
        const int j = jt*16 + n;
        const float bj = (j < Dn) ? b3[j] : 0.f;
        f32x4 oac = (f32x4){bj, bj, bj, bj};
        #pragma unroll 4
        for (int s = 0; s < 16; ++s) {
            const int ks = (s + rot) & 15;
            const int aoff = (ks*64 + lane)*8;
            const short8 ahi = *(const short8*)&sH[aoff];
            const short8 alo = *(const short8*)&sL[aoff];
            const short8 wf  = *(const short8*)&W3P[((size_t)(jt*16 + ks)*64 + lane)*8];
            oac = __builtin_amdgcn_mfma_f32_16x16x32_bf16(ahi, wf, oac, 0, 0, 0);
            oac = __builtin_amdgcn_mfma_f32_16x16x32_bf16(alo, wf, oac, 0, 0, 0);
        }
        if (j < Dn) {
            #pragma unroll
            for (int q = 0; q < 4; ++q)
                out[(size_t)(r0 + kg*4 + q)*Dn + j] = oac[q];
        }
    }
}

extern "C" void kernel_launch(void* const* d_in, const int* in_sizes, int n_in,
                              void* d_out, int out_size, void* d_ws, size_t ws_size,
                              hipStream_t stream)
{
    const float* xs = (const float*)d_in[0];
    const float* t  = (const float*)d_in[1];
    const float* W1 = (const float*)d_in[2];
    const float* b1 = (const float*)d_in[3];
    const float* W2 = (const float*)d_in[4];
    const float* b2 = (const float*)d_in[5];
    const float* W3 = (const float*)d_in[6];
    const float* b3 = (const float*)d_in[7];
    float* out = (float*)d_out;

    char* ws = (char*)d_ws;
    unsigned short* WQ   = (unsigned short*)(ws);                // 1 MB interleaved W2|Cm
    unsigned short* W3P  = (unsigned short*)(ws + 1048576);      // 80 KB
    unsigned short* h1hi = (unsigned short*)(ws + 1130496);      // 4 MB A-frag linear
    unsigned short* s1   = (unsigned short*)(ws + 5324800);      // 4 MB A-frag linear

    k_h1pack<<<586, 512,  0, stream>>>(xs, t, W1, b1, W2, W3, WQ, W3P, h1hi, s1);
    k_BC    <<<256, 1024, 0, stream>>>(h1hi, s1, WQ, b2, W3P, b3, out);
}